// Round 2
// baseline (741.546 us; speedup 1.0000x reference)
//
#include <hip/hip_runtime.h>
#include <cstdint>

#define NN 8192
#define INC 512
#define HIDC 1024
#define OUTC 256

typedef unsigned short u16;
typedef __attribute__((ext_vector_type(8))) __bf16 bf16x8;
typedef __attribute__((ext_vector_type(4))) float f32x4;

__device__ __forceinline__ u16 f32_to_bf16(float f) {
  union { float f; unsigned u; } c; c.f = f;
  unsigned u = c.u;
  u += 0x7fffu + ((u >> 16) & 1u);   // round-to-nearest-even
  return (u16)(u >> 16);
}

// async global->LDS, 16B/lane. LDS dest is wave-uniform base + lane*16.
__device__ __forceinline__ void async_copy16(const void* g, void* l) {
  typedef __attribute__((address_space(1))) const char gch;
  typedef __attribute__((address_space(3))) char lch;
  __builtin_amdgcn_global_load_lds((gch*)(uint64_t)(uintptr_t)g,
                                   (lch*)(uint32_t)(uintptr_t)l, 16, 0, 0);
}

// Fused: deg[i] = sum_j edge[i][j]; isq[i] = deg>0 ? 1/sqrt(deg) : 0;
// Abf[i][j] = bf16(edge[i][j])  (RAW, unnormalized — D^-1/2 scales are folded
// into the GEMM epilogues; valid since relu(s*x) = s*relu(x) for s >= 0).
__global__ __launch_bounds__(256) void rowcvt_k(const float* __restrict__ edge,
                                                float* __restrict__ isq,
                                                u16* __restrict__ Abf) {
  __shared__ float red[4];
  const int row = blockIdx.x;
  const float4* e4 = (const float4*)(edge + (size_t)row * NN);
  ushort4* o4 = (ushort4*)(Abf + (size_t)row * NN);
  float s = 0.f;
#pragma unroll
  for (int it = 0; it < NN / 4 / 256; ++it) {
    float4 v = e4[it * 256 + threadIdx.x];
    s += (v.x + v.y) + (v.z + v.w);
    ushort4 o;
    o.x = f32_to_bf16(v.x);
    o.y = f32_to_bf16(v.y);
    o.z = f32_to_bf16(v.z);
    o.w = f32_to_bf16(v.w);
    o4[it * 256 + threadIdx.x] = o;
  }
  for (int off = 32; off > 0; off >>= 1) s += __shfl_down(s, off, 64);
  if ((threadIdx.x & 63) == 0) red[threadIdx.x >> 6] = s;
  __syncthreads();
  if (threadIdx.x == 0) {
    float t = (red[0] + red[1]) + (red[2] + red[3]);
    isq[row] = (t > 0.f) ? (1.0f / sqrtf(t)) : 0.f;
  }
}

__global__ __launch_bounds__(256) void f2bf_k(const float* __restrict__ in,
                                              u16* __restrict__ out, int n4) {
  int i = blockIdx.x * 256 + threadIdx.x;
  if (i >= n4) return;
  float4 v = ((const float4*)in)[i];
  ushort4 o;
  o.x = f32_to_bf16(v.x);
  o.y = f32_to_bf16(v.y);
  o.z = f32_to_bf16(v.z);
  o.w = f32_to_bf16(v.w);
  ((ushort4*)out)[i] = o;
}

// C[M,N] = act(scale * (A[M,K] * B[N,K]^T + bias[row])); A,B bf16 row-major,
// K%32==0, M,N%128==0. m97 structure: 128x128 tile, BK=32, 4 waves, 4x4
// 16x16x32 MFMA, global_load_lds width=16.
// SROW: multiply output row grow by scale[grow] (before RELU).
// SCOL: multiply output col gcol by scale[gcol] (after bias add).
// SPLIT: blockIdx.z = k-split, fp32 partials at Cout + z*M*N, epilogue deferred.
// SWIZ (needs gridDim.y%8==0): remap blocks so all blocks sharing an A
// row-panel (same y) get the same linear-id%8 -> same XCD under round-robin
// dispatch; A panel then lives in that XCD's L2 and is reused gridDim.x times.
template <bool RELU, bool BIAS, bool OBF16, bool SPLIT, bool SWIZ, bool SROW, bool SCOL>
__global__ __launch_bounds__(256) void gemm_bt(const u16* __restrict__ A,
                                               const u16* __restrict__ B,
                                               const float* __restrict__ bias,
                                               const float* __restrict__ scale,
                                               void* __restrict__ Cout,
                                               const int M, const int N, const int K,
                                               const int Kper) {
  __shared__ __attribute__((aligned(16))) u16 As[128 * 32];
  __shared__ __attribute__((aligned(16))) u16 Bs[128 * 32];
  const int tid = threadIdx.x;
  const int wave = tid >> 6;
  const int lane = tid & 63;

  int bx = blockIdx.x, by = blockIdx.y;
  if (SWIZ) {
    const int i2 = bx + gridDim.x * by;
    const int xcd = i2 & 7;
    const int slot = i2 >> 3;
    const int ypg = gridDim.y >> 3;  // y-panels per XCD
    by = xcd * ypg + (slot % ypg);
    bx = slot / ypg;
  }
  const size_t row0 = (size_t)by * 128;
  const size_t col0 = (size_t)bx * 128;
  const int kbeg = SPLIT ? blockIdx.z * Kper : 0;
  const int klen = SPLIT ? Kper : K;
  const int wm = (wave >> 1) << 6;  // wave quadrant: 64x64
  const int wn = (wave & 1) << 6;

  f32x4 acc[4][4];
  const f32x4 zero = {0.f, 0.f, 0.f, 0.f};
#pragma unroll
  for (int i = 0; i < 4; ++i)
#pragma unroll
    for (int j = 0; j < 4; ++j) acc[i][j] = zero;

  // staging: flat element E = issue*2048 + wave*512 + lane*8; row=E/32 col=E%32
  const int e0 = wave * 512 + lane * 8;
  const int r0 = e0 >> 5;
  const int c0 = e0 & 31;
  const u16* Ab = A + row0 * K + (size_t)r0 * K + c0 + kbeg;
  const u16* Bb = B + col0 * K + (size_t)r0 * K + c0 + kbeg;
  u16* sA0 = &As[wave * 512];
  u16* sA1 = &As[2048 + wave * 512];
  u16* sB0 = &Bs[wave * 512];
  u16* sB1 = &Bs[2048 + wave * 512];
  const size_t K64 = (size_t)64 * K;

  const int fr = lane & 15;    // A: m, B: n  (lane&15)
  const int quad = lane >> 4;  // k = quad*8 + j
  const int aoff = (wm + fr) * 32 + quad * 8;
  const int boff = (wn + fr) * 32 + quad * 8;

  for (int kt = 0; kt < klen; kt += 32) {
    async_copy16(Ab + kt, sA0);
    async_copy16(Ab + K64 + kt, sA1);
    async_copy16(Bb + kt, sB0);
    async_copy16(Bb + K64 + kt, sB1);
    __syncthreads();  // drains vmcnt -> LDS visible
    bf16x8 af[4], bfr[4];
#pragma unroll
    for (int i = 0; i < 4; ++i) {
      af[i] = *(const bf16x8*)&As[aoff + i * 512];
      bfr[i] = *(const bf16x8*)&Bs[boff + i * 512];
    }
#pragma unroll
    for (int i = 0; i < 4; ++i)
#pragma unroll
      for (int j = 0; j < 4; ++j)
        acc[i][j] = __builtin_amdgcn_mfma_f32_16x16x32_bf16(af[i], bfr[j], acc[i][j], 0, 0, 0);
    __syncthreads();
  }

  // C/D layout (verified m89/m91): col = lane&15, row = (lane>>4)*4 + reg
  float* Pf = SPLIT ? ((float*)Cout + (size_t)blockIdx.z * M * N) : (float*)Cout;
#pragma unroll
  for (int i = 0; i < 4; ++i) {
#pragma unroll
    for (int r = 0; r < 4; ++r) {
      const size_t grow = row0 + wm + i * 16 + quad * 4 + r;
      float bv = 0.f;
      if (BIAS && !SPLIT) bv = bias[grow];
      float rs = 1.f;
      if (SROW && !SPLIT) rs = scale[grow];
#pragma unroll
      for (int j = 0; j < 4; ++j) {
        const size_t gcol = col0 + wn + j * 16 + fr;
        float v = acc[i][j][r] + bv;
        if (SPLIT) {
          Pf[grow * N + gcol] = v;
        } else {
          if (SCOL) v *= scale[gcol];
          if (SROW) v *= rs;
          if (RELU) v = fmaxf(v, 0.f);
          if (OBF16)
            ((u16*)Cout)[grow * N + gcol] = f32_to_bf16(v);
          else
            ((float*)Cout)[grow * N + gcol] = v;
        }
      }
    }
  }
}

// out = act( scale * (sum_s part[s] + bias) ), vectorized float4 per thread.
// SROW: scale[row] (all 4 elems same row, requires N%4==0). SCOL: scale[col..col+3].
template <bool RELU, bool BIAS, bool OBF16, bool SROW, bool SCOL>
__global__ __launch_bounds__(256) void reduce_k(const float* __restrict__ part,
                                                const float* __restrict__ bias,
                                                const float* __restrict__ scale,
                                                void* __restrict__ out,
                                                const int M, const int N, const int ks) {
  const size_t MN4 = (size_t)M * N / 4;
  const size_t i4 = (size_t)blockIdx.x * 256 + threadIdx.x;
  if (i4 >= MN4) return;
  const float4* p4 = (const float4*)part;
  float4 s = p4[i4];
  for (int k = 1; k < ks; ++k) {
    float4 v = p4[(size_t)k * MN4 + i4];
    s.x += v.x; s.y += v.y; s.z += v.z; s.w += v.w;
  }
  const int row = (int)((i4 * 4) / N);
  if (BIAS) {
    const float b = bias[row];
    s.x += b; s.y += b; s.z += b; s.w += b;
  }
  if (SCOL) {
    const float4 sc = ((const float4*)scale)[i4 % (size_t)(N / 4)];
    s.x *= sc.x; s.y *= sc.y; s.z *= sc.z; s.w *= sc.w;
  }
  if (SROW) {
    const float r = scale[row];
    s.x *= r; s.y *= r; s.z *= r; s.w *= r;
  }
  if (RELU) {
    s.x = fmaxf(s.x, 0.f); s.y = fmaxf(s.y, 0.f);
    s.z = fmaxf(s.z, 0.f); s.w = fmaxf(s.w, 0.f);
  }
  if (OBF16) {
    ushort4 o;
    o.x = f32_to_bf16(s.x); o.y = f32_to_bf16(s.y);
    o.z = f32_to_bf16(s.z); o.w = f32_to_bf16(s.w);
    ((ushort4*)out)[i4] = o;
  } else {
    ((float4*)out)[i4] = s;
  }
}

extern "C" void kernel_launch(void* const* d_in, const int* in_sizes, int n_in,
                              void* d_out, int out_size, void* d_ws, size_t ws_size,
                              hipStream_t stream) {
  const float* point = (const float*)d_in[0];
  const float* edge  = (const float*)d_in[1];
  const float* W1    = (const float*)d_in[2];
  const float* b1    = (const float*)d_in[3];
  const float* W2    = (const float*)d_in[4];
  const float* b2    = (const float*)d_in[5];
  float* out = (float*)d_out;

  char* ws = (char*)d_ws;
  size_t off = 0;
  auto alloc = [&](size_t bytes) -> void* {
    void* p = ws + off;
    off += (bytes + 255) & ~(size_t)255;
    return p;
  };
  float* isq  = (float*)alloc((size_t)NN * 4);
  u16* Abf    = (u16*)alloc((size_t)NN * NN * 2);        // 128 MB (raw bf16 edge)
  // scratch (64 MB): pbf early; split-K partials reuse serially.
  char* scratch = (char*)alloc((size_t)64 * 1024 * 1024);
  u16* w1bf   = (u16*)alloc((size_t)HIDC * INC * 2);     // 1 MB
  u16* w2bf   = (u16*)alloc((size_t)OUTC * HIDC * 2);    // 0.5 MB
  u16* Ht     = (u16*)alloc((size_t)HIDC * NN * 2);      // 16 MB  (isq-scaled h1^T)
  u16* h2     = (u16*)alloc((size_t)NN * HIDC * 2);      // 16 MB  (relu(A_n h1))
  u16* O1t    = (u16*)alloc((size_t)OUTC * NN * 2);      // 4 MB   (isq-scaled o1^T)
  const bool have_ws = off <= ws_size;  // deterministic -> graph-safe

  u16* pbf = (u16*)scratch;             // 8 MB, dead after gemm1
  float* part = (float*)scratch;        // split-K partials

  // One pass over edge: rowsums (-> isq) + raw bf16 conversion.
  rowcvt_k<<<NN, 256, 0, stream>>>(edge, isq, Abf);
  f2bf_k<<<(NN * INC / 4) / 256, 256, 0, stream>>>(point, pbf, NN * INC / 4);
  f2bf_k<<<(HIDC * INC / 4) / 256, 256, 0, stream>>>(W1, w1bf, HIDC * INC / 4);
  f2bf_k<<<(OUTC * HIDC / 4) / 256, 256, 0, stream>>>(W2, w2bf, OUTC * HIDC / 4);

  // Ht[c][n] = isq[n] * (sum_k W1[c][k] point[n][k] + b1[c])  (bf16) — 512 blocks
  gemm_bt<false, true, true, false, false, false, true>
      <<<dim3(NN / 128, HIDC / 128), 256, 0, stream>>>(
      w1bf, pbf, b1, isq, Ht, HIDC, NN, INC, INC);

  if (have_ws) {
    // h2 = relu(isq[i] * (Abf @ Ht^T)): split-K 2 -> 1024 blocks (4/CU, vs 512
    // blocks = 2/CU non-split which measured 580 TF / 21% occupancy). Epilogue
    // (row scale + relu + bf16) moves to reduce_k. Partials 2x32 MB = scratch.
    gemm_bt<false, false, false, true, true, false, false>
        <<<dim3(HIDC / 128, NN / 128, 2), 256, 0, stream>>>(
        Abf, Ht, nullptr, nullptr, part, NN, HIDC, NN, NN / 2);
    reduce_k<true, false, true, true, false><<<(NN * HIDC / 4) / 256, 256, 0, stream>>>(
        part, nullptr, isq, h2, NN, HIDC, 2);

    // O1t[c][n] = isq[n]*(W2 @ h2^T + b2): split-K 4 -> 512 blocks of 128x128xK256
    gemm_bt<false, false, false, true, false, false, false>
        <<<dim3(NN / 128, OUTC / 128, 4), 256, 0, stream>>>(
        w2bf, h2, nullptr, nullptr, part, OUTC, NN, HIDC, HIDC / 4);
    reduce_k<false, true, true, false, true><<<(OUTC * NN / 4) / 256, 256, 0, stream>>>(
        part, b2, isq, O1t, OUTC, NN, 4);
    // out = relu(isq[i] * (Abf @ O1t^T)): split-K 8 -> 1024 blocks, swizzled
    gemm_bt<false, false, false, true, true, false, false>
        <<<dim3(OUTC / 128, NN / 128, 8), 256, 0, stream>>>(
        Abf, O1t, nullptr, nullptr, part, NN, OUTC, NN, NN / 8);
    reduce_k<true, false, false, true, false><<<(NN * OUTC / 4) / 256, 256, 0, stream>>>(
        part, nullptr, isq, out, NN, OUTC, 8);
  } else {
    // fallback: non-split path (no scratch partials)
    gemm_bt<true, false, true, false, true, true, false>
        <<<dim3(HIDC / 128, NN / 128), 256, 0, stream>>>(
        Abf, Ht, nullptr, isq, h2, NN, HIDC, NN, NN);
    gemm_bt<false, true, true, false, false, false, true>
        <<<dim3(NN / 128, OUTC / 128), 256, 0, stream>>>(
        w2bf, h2, b2, isq, O1t, OUTC, NN, HIDC, HIDC);
    gemm_bt<true, false, false, false, true, true, false>
        <<<dim3(OUTC / 128, NN / 128), 256, 0, stream>>>(
        Abf, O1t, nullptr, isq, out, NN, OUTC, NN, NN);
  }
}

// Round 3
// 677.631 us; speedup vs baseline: 1.0943x; 1.0943x over previous
//
#include <hip/hip_runtime.h>
#include <cstdint>

#define NN 8192
#define INC 512
#define HIDC 1024
#define OUTC 256

typedef unsigned short u16;
typedef __attribute__((ext_vector_type(8))) __bf16 bf16x8;
typedef __attribute__((ext_vector_type(4))) float f32x4;

__device__ __forceinline__ u16 f32_to_bf16(float f) {
  union { float f; unsigned u; } c; c.f = f;
  unsigned u = c.u;
  u += 0x7fffu + ((u >> 16) & 1u);   // round-to-nearest-even
  return (u16)(u >> 16);
}

// async global->LDS, 16B/lane. LDS dest is wave-uniform base + lane*16.
__device__ __forceinline__ void async_copy16(const void* g, void* l) {
  typedef __attribute__((address_space(1))) const char gch;
  typedef __attribute__((address_space(3))) char lch;
  __builtin_amdgcn_global_load_lds((gch*)(uint64_t)(uintptr_t)g,
                                   (lch*)(uint32_t)(uintptr_t)l, 16, 0, 0);
}

// Fused: deg[i] = sum_j edge[i][j]; isq[i] = deg>0 ? 1/sqrt(deg) : 0;
// Abf[i][j] = bf16(edge[i][j])  (RAW, unnormalized — D^-1/2 scales are folded
// into the GEMM epilogues; valid since relu(s*x) = s*relu(x) for s >= 0).
__global__ __launch_bounds__(256) void rowcvt_k(const float* __restrict__ edge,
                                                float* __restrict__ isq,
                                                u16* __restrict__ Abf) {
  __shared__ float red[4];
  const int row = blockIdx.x;
  const float4* e4 = (const float4*)(edge + (size_t)row * NN);
  ushort4* o4 = (ushort4*)(Abf + (size_t)row * NN);
  float s = 0.f;
#pragma unroll
  for (int it = 0; it < NN / 4 / 256; ++it) {
    float4 v = e4[it * 256 + threadIdx.x];
    s += (v.x + v.y) + (v.z + v.w);
    ushort4 o;
    o.x = f32_to_bf16(v.x);
    o.y = f32_to_bf16(v.y);
    o.z = f32_to_bf16(v.z);
    o.w = f32_to_bf16(v.w);
    o4[it * 256 + threadIdx.x] = o;
  }
  for (int off = 32; off > 0; off >>= 1) s += __shfl_down(s, off, 64);
  if ((threadIdx.x & 63) == 0) red[threadIdx.x >> 6] = s;
  __syncthreads();
  if (threadIdx.x == 0) {
    float t = (red[0] + red[1]) + (red[2] + red[3]);
    isq[row] = (t > 0.f) ? (1.0f / sqrtf(t)) : 0.f;
  }
}

__global__ __launch_bounds__(256) void f2bf_k(const float* __restrict__ in,
                                              u16* __restrict__ out, int n4) {
  int i = blockIdx.x * 256 + threadIdx.x;
  if (i >= n4) return;
  float4 v = ((const float4*)in)[i];
  ushort4 o;
  o.x = f32_to_bf16(v.x);
  o.y = f32_to_bf16(v.y);
  o.z = f32_to_bf16(v.z);
  o.w = f32_to_bf16(v.w);
  ((ushort4*)out)[i] = o;
}

// ---------------------------------------------------------------------------
// Pipelined GEMM: C[M,N] = relu(scale[row] * (A[M,K] @ B[N,K]^T)) -> bf16.
// BM=256, BN=128, BK=32, 8 waves (4M x 2N, 64x64 per wave like the proven
// kernel), depth-4 LDS pipeline (96 KB), counted vmcnt (never drains to 0 in
// the main loop), raw s_barrier. 1 block/CU. Round-2 evidence showed the
// 2-barrier __syncthreads structure serializes on per-K-step load latency
// (~1100 cy/step regardless of blocks/CU); here loads for tile t+4 are issued
// after tile t's read-done barrier, giving ~3 iterations of latency cover.
// Race safety: buf[t%4] overwritten only by issues placed after the barrier
// where all waves finished reading it; reads gated by per-wave vmcnt(9) +
// barrier (so every wave's tile-t loads are complete chip-visible in LDS).
// ---------------------------------------------------------------------------
template <bool SWIZ>
__global__ __launch_bounds__(512, 2) void gemm_pipe(const u16* __restrict__ A,
                                                    const u16* __restrict__ B,
                                                    const float* __restrict__ scale,
                                                    u16* __restrict__ C,
                                                    const int M, const int N,
                                                    const int K) {
  // per buffer: A 256x32 (8192 elems) + B 128x32 (4096 elems) = 24 KB
  __shared__ __attribute__((aligned(16))) u16 S[4 * 12288];
  const int tid = threadIdx.x;
  const int wave = tid >> 6;
  const int lane = tid & 63;

  int bx = blockIdx.x, by = blockIdx.y;
  if (SWIZ) {  // gridDim.y % 8 == 0; same-y blocks share one XCD's L2
    const int i2 = bx + gridDim.x * by;
    const int xcd = i2 & 7;
    const int slot = i2 >> 3;
    const int ypg = gridDim.y >> 3;
    by = xcd * ypg + (slot % ypg);
    bx = slot / ypg;
  }
  const size_t row0 = (size_t)by * 256;
  const size_t col0 = (size_t)bx * 128;
  const int wm = wave >> 1;   // 0..3 -> A rows wm*64
  const int wn = wave & 1;    // 0..1 -> B cols wn*64
  const int fr = lane & 15;
  const int quad = lane >> 4;

  f32x4 acc[4][4];
  const f32x4 zero = {0.f, 0.f, 0.f, 0.f};
#pragma unroll
  for (int i = 0; i < 4; ++i)
#pragma unroll
    for (int j = 0; j < 4; ++j) acc[i][j] = zero;

  // staging map: flat elem E = wave*512 + lane*8; row=E/32, col=E%32.
  // A needs 2 rounds (rows 0-127, 128-255), B one round (rows 0-127).
  const int eA = wave * 512 + lane * 8;
  const int ar = eA >> 5;
  const int ac = eA & 31;
  const u16* Ag = A + (row0 + ar) * K + ac;
  const u16* Bg = B + (col0 + ar) * K + ac;
  const size_t K128 = (size_t)128 * K;
  const int NT = K / 32;

  // prologue: stage tiles 0..3 into buffers 0..3 (3 loads/wave each)
#pragma unroll
  for (int p = 0; p < 4; ++p) {
    if (p < NT) {
      u16* sb = &S[p * 12288 + wave * 512];
      const int kt = p * 32;
      async_copy16(Ag + kt, sb);
      async_copy16(Ag + K128 + kt, sb + 4096);
      async_copy16(Bg + kt, sb + 8192);
    }
  }

  const int aoff = (wm * 64 + fr) * 32 + quad * 8;
  const int boff = 8192 + (wn * 64 + fr) * 32 + quad * 8;

  for (int t = 0; t < NT; ++t) {
    // 3 tiles (9 loads) may stay in flight; tile t (and older) must be done.
    asm volatile("s_waitcnt vmcnt(9)" ::: "memory");
    __builtin_amdgcn_sched_barrier(0);
    __builtin_amdgcn_s_barrier();  // now ALL waves' tile-t loads are in LDS
    asm volatile("" ::: "memory");
    const u16* Sb = &S[(t & 3) * 12288];
    bf16x8 af[4], bfv[4];
#pragma unroll
    for (int i = 0; i < 4; ++i) {
      af[i] = *(const bf16x8*)&Sb[aoff + i * 512];
      bfv[i] = *(const bf16x8*)&Sb[boff + i * 512];
    }
#pragma unroll
    for (int i = 0; i < 4; ++i)
#pragma unroll
      for (int j = 0; j < 4; ++j)
        acc[i][j] = __builtin_amdgcn_mfma_f32_16x16x32_bf16(af[i], bfv[j], acc[i][j], 0, 0, 0);
    __builtin_amdgcn_sched_barrier(0);
    asm volatile("" ::: "memory");
    __builtin_amdgcn_s_barrier();  // all waves done reading buf[t&3]
    __builtin_amdgcn_sched_barrier(0);
    if (t + 4 < NT) {  // refill buf[t&3] with tile t+4
      u16* sb = &S[(t & 3) * 12288 + wave * 512];
      const int kt = (t + 4) * 32;
      async_copy16(Ag + kt, sb);
      async_copy16(Ag + K128 + kt, sb + 4096);
      async_copy16(Bg + kt, sb + 8192);
    }
  }

  // C/D layout (verified m89/m91): col = lane&15, row = (lane>>4)*4 + reg
#pragma unroll
  for (int i = 0; i < 4; ++i) {
#pragma unroll
    for (int r = 0; r < 4; ++r) {
      const size_t grow = row0 + wm * 64 + i * 16 + quad * 4 + r;
      const float rs = scale[grow];
#pragma unroll
      for (int j = 0; j < 4; ++j) {
        const size_t gcol = col0 + wn * 64 + j * 16 + fr;
        float v = fmaxf(acc[i][j][r] * rs, 0.f);
        C[grow * N + gcol] = f32_to_bf16(v);
      }
    }
  }
}

// C[M,N] = act(scale * (A[M,K] * B[N,K]^T + bias[row])); A,B bf16 row-major,
// K%32==0, M,N%128==0. m97 structure: 128x128 tile, BK=32, 4 waves, 4x4
// 16x16x32 MFMA, global_load_lds width=16.
template <bool RELU, bool BIAS, bool OBF16, bool SPLIT, bool SWIZ, bool SROW, bool SCOL>
__global__ __launch_bounds__(256) void gemm_bt(const u16* __restrict__ A,
                                               const u16* __restrict__ B,
                                               const float* __restrict__ bias,
                                               const float* __restrict__ scale,
                                               void* __restrict__ Cout,
                                               const int M, const int N, const int K,
                                               const int Kper) {
  __shared__ __attribute__((aligned(16))) u16 As[128 * 32];
  __shared__ __attribute__((aligned(16))) u16 Bs[128 * 32];
  const int tid = threadIdx.x;
  const int wave = tid >> 6;
  const int lane = tid & 63;

  int bx = blockIdx.x, by = blockIdx.y;
  if (SWIZ) {
    const int i2 = bx + gridDim.x * by;
    const int xcd = i2 & 7;
    const int slot = i2 >> 3;
    const int ypg = gridDim.y >> 3;  // y-panels per XCD
    by = xcd * ypg + (slot % ypg);
    bx = slot / ypg;
  }
  const size_t row0 = (size_t)by * 128;
  const size_t col0 = (size_t)bx * 128;
  const int kbeg = SPLIT ? blockIdx.z * Kper : 0;
  const int klen = SPLIT ? Kper : K;
  const int wm = (wave >> 1) << 6;  // wave quadrant: 64x64
  const int wn = (wave & 1) << 6;

  f32x4 acc[4][4];
  const f32x4 zero = {0.f, 0.f, 0.f, 0.f};
#pragma unroll
  for (int i = 0; i < 4; ++i)
#pragma unroll
    for (int j = 0; j < 4; ++j) acc[i][j] = zero;

  // staging: flat element E = issue*2048 + wave*512 + lane*8; row=E/32 col=E%32
  const int e0 = wave * 512 + lane * 8;
  const int r0 = e0 >> 5;
  const int c0 = e0 & 31;
  const u16* Ab = A + row0 * K + (size_t)r0 * K + c0 + kbeg;
  const u16* Bb = B + col0 * K + (size_t)r0 * K + c0 + kbeg;
  u16* sA0 = &As[wave * 512];
  u16* sA1 = &As[2048 + wave * 512];
  u16* sB0 = &Bs[wave * 512];
  u16* sB1 = &Bs[2048 + wave * 512];
  const size_t K64 = (size_t)64 * K;

  const int fr = lane & 15;    // A: m, B: n  (lane&15)
  const int quad = lane >> 4;  // k = quad*8 + j
  const int aoff = (wm + fr) * 32 + quad * 8;
  const int boff = (wn + fr) * 32 + quad * 8;

  for (int kt = 0; kt < klen; kt += 32) {
    async_copy16(Ab + kt, sA0);
    async_copy16(Ab + K64 + kt, sA1);
    async_copy16(Bb + kt, sB0);
    async_copy16(Bb + K64 + kt, sB1);
    __syncthreads();  // drains vmcnt -> LDS visible
    bf16x8 af[4], bfr[4];
#pragma unroll
    for (int i = 0; i < 4; ++i) {
      af[i] = *(const bf16x8*)&As[aoff + i * 512];
      bfr[i] = *(const bf16x8*)&Bs[boff + i * 512];
    }
#pragma unroll
    for (int i = 0; i < 4; ++i)
#pragma unroll
      for (int j = 0; j < 4; ++j)
        acc[i][j] = __builtin_amdgcn_mfma_f32_16x16x32_bf16(af[i], bfr[j], acc[i][j], 0, 0, 0);
    __syncthreads();
  }

  // C/D layout (verified m89/m91): col = lane&15, row = (lane>>4)*4 + reg
  float* Pf = SPLIT ? ((float*)Cout + (size_t)blockIdx.z * M * N) : (float*)Cout;
#pragma unroll
  for (int i = 0; i < 4; ++i) {
#pragma unroll
    for (int r = 0; r < 4; ++r) {
      const size_t grow = row0 + wm + i * 16 + quad * 4 + r;
      float bv = 0.f;
      if (BIAS && !SPLIT) bv = bias[grow];
      float rs = 1.f;
      if (SROW && !SPLIT) rs = scale[grow];
#pragma unroll
      for (int j = 0; j < 4; ++j) {
        const size_t gcol = col0 + wn + j * 16 + fr;
        float v = acc[i][j][r] + bv;
        if (SPLIT) {
          Pf[grow * N + gcol] = v;
        } else {
          if (SCOL) v *= scale[gcol];
          if (SROW) v *= rs;
          if (RELU) v = fmaxf(v, 0.f);
          if (OBF16)
            ((u16*)Cout)[grow * N + gcol] = f32_to_bf16(v);
          else
            ((float*)Cout)[grow * N + gcol] = v;
        }
      }
    }
  }
}

// out = act( scale * (sum_s part[s] + bias) ), vectorized float4 per thread.
template <bool RELU, bool BIAS, bool OBF16, bool SROW, bool SCOL>
__global__ __launch_bounds__(256) void reduce_k(const float* __restrict__ part,
                                                const float* __restrict__ bias,
                                                const float* __restrict__ scale,
                                                void* __restrict__ out,
                                                const int M, const int N, const int ks) {
  const size_t MN4 = (size_t)M * N / 4;
  const size_t i4 = (size_t)blockIdx.x * 256 + threadIdx.x;
  if (i4 >= MN4) return;
  const float4* p4 = (const float4*)part;
  float4 s = p4[i4];
  for (int k = 1; k < ks; ++k) {
    float4 v = p4[(size_t)k * MN4 + i4];
    s.x += v.x; s.y += v.y; s.z += v.z; s.w += v.w;
  }
  const int row = (int)((i4 * 4) / N);
  if (BIAS) {
    const float b = bias[row];
    s.x += b; s.y += b; s.z += b; s.w += b;
  }
  if (SCOL) {
    const float4 sc = ((const float4*)scale)[i4 % (size_t)(N / 4)];
    s.x *= sc.x; s.y *= sc.y; s.z *= sc.z; s.w *= sc.w;
  }
  if (SROW) {
    const float r = scale[row];
    s.x *= r; s.y *= r; s.z *= r; s.w *= r;
  }
  if (RELU) {
    s.x = fmaxf(s.x, 0.f); s.y = fmaxf(s.y, 0.f);
    s.z = fmaxf(s.z, 0.f); s.w = fmaxf(s.w, 0.f);
  }
  if (OBF16) {
    ushort4 o;
    o.x = f32_to_bf16(s.x); o.y = f32_to_bf16(s.y);
    o.z = f32_to_bf16(s.z); o.w = f32_to_bf16(s.w);
    ((ushort4*)out)[i4] = o;
  } else {
    ((float4*)out)[i4] = s;
  }
}

extern "C" void kernel_launch(void* const* d_in, const int* in_sizes, int n_in,
                              void* d_out, int out_size, void* d_ws, size_t ws_size,
                              hipStream_t stream) {
  const float* point = (const float*)d_in[0];
  const float* edge  = (const float*)d_in[1];
  const float* W1    = (const float*)d_in[2];
  const float* b1    = (const float*)d_in[3];
  const float* W2    = (const float*)d_in[4];
  const float* b2    = (const float*)d_in[5];
  float* out = (float*)d_out;

  char* ws = (char*)d_ws;
  size_t off = 0;
  auto alloc = [&](size_t bytes) -> void* {
    void* p = ws + off;
    off += (bytes + 255) & ~(size_t)255;
    return p;
  };
  float* isq  = (float*)alloc((size_t)NN * 4);
  u16* Abf    = (u16*)alloc((size_t)NN * NN * 2);        // 128 MB (raw bf16 edge)
  // scratch (64 MB): pbf early; split-K partials reuse serially.
  char* scratch = (char*)alloc((size_t)64 * 1024 * 1024);
  u16* w1bf   = (u16*)alloc((size_t)HIDC * INC * 2);     // 1 MB
  u16* w2bf   = (u16*)alloc((size_t)OUTC * HIDC * 2);    // 0.5 MB
  u16* Ht     = (u16*)alloc((size_t)HIDC * NN * 2);      // 16 MB  (isq-scaled h1^T)
  u16* h2     = (u16*)alloc((size_t)NN * HIDC * 2);      // 16 MB  (relu(A_n h1))
  u16* O1t    = (u16*)alloc((size_t)OUTC * NN * 2);      // 4 MB   (isq-scaled o1^T)
  const bool have_ws = off <= ws_size;  // deterministic -> graph-safe

  u16* pbf = (u16*)scratch;             // 8 MB, dead after gemm1
  float* part = (float*)scratch;        // split-K partials

  // One pass over edge: rowsums (-> isq) + raw bf16 conversion.
  rowcvt_k<<<NN, 256, 0, stream>>>(edge, isq, Abf);
  f2bf_k<<<(NN * INC / 4) / 256, 256, 0, stream>>>(point, pbf, NN * INC / 4);
  f2bf_k<<<(HIDC * INC / 4) / 256, 256, 0, stream>>>(W1, w1bf, HIDC * INC / 4);
  f2bf_k<<<(OUTC * HIDC / 4) / 256, 256, 0, stream>>>(W2, w2bf, OUTC * HIDC / 4);

  // Ht[c][n] = isq[n] * (sum_k W1[c][k] point[n][k] + b1[c])  (bf16) — 512 blocks
  gemm_bt<false, true, true, false, false, false, true>
      <<<dim3(NN / 128, HIDC / 128), 256, 0, stream>>>(
      w1bf, pbf, b1, isq, Ht, HIDC, NN, INC, INC);

  // h2 = relu(isq[i] * (Abf @ Ht^T)): depth-4 pipelined 256x128 kernel,
  // grid 8x32 = 256 blocks = 1/CU, counted vmcnt, fused epilogue, swizzled.
  gemm_pipe<true><<<dim3(HIDC / 128, NN / 256), 512, 0, stream>>>(
      Abf, Ht, isq, h2, NN, HIDC, NN);

  if (have_ws) {
    // O1t[c][n] = isq[n]*(W2 @ h2^T + b2): split-K 4 -> 512 blocks of 128x128xK256
    gemm_bt<false, false, false, true, false, false, false>
        <<<dim3(NN / 128, OUTC / 128, 4), 256, 0, stream>>>(
        w2bf, h2, nullptr, nullptr, part, OUTC, NN, HIDC, HIDC / 4);
    reduce_k<false, true, true, false, true><<<(OUTC * NN / 4) / 256, 256, 0, stream>>>(
        part, b2, isq, O1t, OUTC, NN, 4);
    // out = relu(isq[i] * (Abf @ O1t^T)): split-K 8 -> 1024 blocks, swizzled
    gemm_bt<false, false, false, true, true, false, false>
        <<<dim3(OUTC / 128, NN / 128, 8), 256, 0, stream>>>(
        Abf, O1t, nullptr, nullptr, part, NN, OUTC, NN, NN / 8);
    reduce_k<true, false, false, true, false><<<(NN * OUTC / 4) / 256, 256, 0, stream>>>(
        part, nullptr, isq, out, NN, OUTC, 8);
  } else {
    // fallback: non-split path (no scratch partials)
    gemm_bt<false, true, true, false, false, false, true>
        <<<dim3(NN / 128, OUTC / 128), 256, 0, stream>>>(
        w2bf, h2, b2, isq, O1t, OUTC, NN, HIDC, HIDC);
    gemm_bt<true, false, false, false, true, true, false>
        <<<dim3(OUTC / 128, NN / 128), 256, 0, stream>>>(
        Abf, O1t, nullptr, isq, out, NN, OUTC, NN, NN);
  }
}

// Round 4
// 640.709 us; speedup vs baseline: 1.1574x; 1.0576x over previous
//
#include <hip/hip_runtime.h>
#include <cstdint>

#define NN 8192
#define INC 512
#define HIDC 1024
#define OUTC 256

typedef unsigned short u16;
typedef __attribute__((ext_vector_type(8))) __bf16 bf16x8;
typedef __attribute__((ext_vector_type(4))) float f32x4;

__device__ __forceinline__ u16 f32_to_bf16(float f) {
  union { float f; unsigned u; } c; c.f = f;
  unsigned u = c.u;
  u += 0x7fffu + ((u >> 16) & 1u);   // round-to-nearest-even
  return (u16)(u >> 16);
}

// async global->LDS, 16B/lane. LDS dest is wave-uniform base + lane*16.
__device__ __forceinline__ void async_copy16(const void* g, void* l) {
  typedef __attribute__((address_space(1))) const char gch;
  typedef __attribute__((address_space(3))) char lch;
  __builtin_amdgcn_global_load_lds((gch*)(uint64_t)(uintptr_t)g,
                                   (lch*)(uint32_t)(uintptr_t)l, 16, 0, 0);
}

// Fused: deg[i] = sum_j edge[i][j]; isq[i] = deg>0 ? 1/sqrt(deg) : 0;
// Abf[i][j] = bf16(edge[i][j])  (RAW, unnormalized — D^-1/2 scales are folded
// into the GEMM epilogues; valid since relu(s*x) = s*relu(x) for s >= 0).
__global__ __launch_bounds__(256) void rowcvt_k(const float* __restrict__ edge,
                                                float* __restrict__ isq,
                                                u16* __restrict__ Abf) {
  __shared__ float red[4];
  const int row = blockIdx.x;
  const float4* e4 = (const float4*)(edge + (size_t)row * NN);
  ushort4* o4 = (ushort4*)(Abf + (size_t)row * NN);
  float s = 0.f;
#pragma unroll
  for (int it = 0; it < NN / 4 / 256; ++it) {
    float4 v = e4[it * 256 + threadIdx.x];
    s += (v.x + v.y) + (v.z + v.w);
    ushort4 o;
    o.x = f32_to_bf16(v.x);
    o.y = f32_to_bf16(v.y);
    o.z = f32_to_bf16(v.z);
    o.w = f32_to_bf16(v.w);
    o4[it * 256 + threadIdx.x] = o;
  }
  for (int off = 32; off > 0; off >>= 1) s += __shfl_down(s, off, 64);
  if ((threadIdx.x & 63) == 0) red[threadIdx.x >> 6] = s;
  __syncthreads();
  if (threadIdx.x == 0) {
    float t = (red[0] + red[1]) + (red[2] + red[3]);
    isq[row] = (t > 0.f) ? (1.0f / sqrtf(t)) : 0.f;
  }
}

__global__ __launch_bounds__(256) void f2bf_k(const float* __restrict__ in,
                                              u16* __restrict__ out, int n4) {
  int i = blockIdx.x * 256 + threadIdx.x;
  if (i >= n4) return;
  float4 v = ((const float4*)in)[i];
  ushort4 o;
  o.x = f32_to_bf16(v.x);
  o.y = f32_to_bf16(v.y);
  o.z = f32_to_bf16(v.z);
  o.w = f32_to_bf16(v.w);
  ((ushort4*)out)[i] = o;
}

// ---------------------------------------------------------------------------
// Pipelined GEMM, 128x128 tile, 2 blocks/CU:
// C[M,N] = act(scale*(A[M,K] @ B[N,K]^T + bias)); A,B bf16 row-major.
// 4 waves (64x64 quadrant each, 4x4 16x16x32 MFMA), depth-4 LDS pipeline
// (4 x 16 KB = 64 KB -> two blocks co-resident per CU), counted vmcnt(12)
// (4 loads/wave/tile, 3 tiles in flight; never drained to 0 in the loop),
// raw s_barrier. R3 evidence: depth-4 @ 1 block/CU = 727 TF, still
// ~1000 cy/step of convoy stall; second independent block per CU (m114
// inter-block overlap) absorbs it.
// Race safety (same structure as R3, which passed): buf[t&3] is refilled only
// after the barrier at which all waves finished reading tile t; reads are
// gated by per-wave vmcnt(12) + barrier (all waves' tile-t loads in LDS).
// ---------------------------------------------------------------------------
template <bool RELU, bool BIAS, bool OBF16, bool SPLIT, bool SWIZ, bool SROW, bool SCOL>
__global__ __launch_bounds__(256, 2) void gemm_pipe(const u16* __restrict__ A,
                                                    const u16* __restrict__ B,
                                                    const float* __restrict__ bias,
                                                    const float* __restrict__ scale,
                                                    void* __restrict__ Cout,
                                                    const int M, const int N,
                                                    const int K, const int Kper) {
  // buffer p: A tile 128x32 at [p*8192, +4096), B tile 128x32 at +4096.
  __shared__ __attribute__((aligned(16))) u16 S[4 * 8192];
  const int tid = threadIdx.x;
  const int wave = tid >> 6;
  const int lane = tid & 63;

  int bx = blockIdx.x, by = blockIdx.y;
  if (SWIZ) {  // gridDim.y % 8 == 0; same-y blocks share one XCD's L2
    const int i2 = bx + gridDim.x * by;
    const int xcd = i2 & 7;
    const int slot = i2 >> 3;
    const int ypg = gridDim.y >> 3;
    by = xcd * ypg + (slot % ypg);
    bx = slot / ypg;
  }
  const size_t row0 = (size_t)by * 128;
  const size_t col0 = (size_t)bx * 128;
  const int kbeg = SPLIT ? blockIdx.z * Kper : 0;
  const int klen = SPLIT ? Kper : K;
  const int NT = klen / 32;
  const int wm = (wave >> 1) << 6;  // wave quadrant: 64x64
  const int wn = (wave & 1) << 6;

  f32x4 acc[4][4];
  const f32x4 zero = {0.f, 0.f, 0.f, 0.f};
#pragma unroll
  for (int i = 0; i < 4; ++i)
#pragma unroll
    for (int j = 0; j < 4; ++j) acc[i][j] = zero;

  // staging map: flat elem E = wave*512 + lane*8; row=E/32, col=E%32;
  // two issues each for A and B cover rows 0-63 / 64-127.
  const int e0 = wave * 512 + lane * 8;
  const int r0 = e0 >> 5;
  const int c0 = e0 & 31;
  const u16* Ab = A + (row0 + r0) * K + c0 + kbeg;
  const u16* Bb = B + (col0 + r0) * K + c0 + kbeg;
  const size_t K64 = (size_t)64 * K;

  // prologue: stage tiles 0..3 into buffers 0..3 (4 loads/wave each)
#pragma unroll
  for (int p = 0; p < 4; ++p) {
    if (p < NT) {
      u16* base = &S[p * 8192 + wave * 512];
      const int kt = p * 32;
      async_copy16(Ab + kt, base);
      async_copy16(Ab + K64 + kt, base + 2048);
      async_copy16(Bb + kt, base + 4096);
      async_copy16(Bb + K64 + kt, base + 6144);
    }
  }

  const int fr = lane & 15;
  const int quad = lane >> 4;
  const int aoff = (wm + fr) * 32 + quad * 8;
  const int boff = 4096 + (wn + fr) * 32 + quad * 8;

  for (int t = 0; t < NT; ++t) {
    // 3 newer tiles (12 loads) may stay in flight; tile t must be done.
    asm volatile("s_waitcnt vmcnt(12)" ::: "memory");
    __builtin_amdgcn_sched_barrier(0);
    __builtin_amdgcn_s_barrier();  // now ALL waves' tile-t loads are in LDS
    asm volatile("" ::: "memory");
    const u16* Sb = &S[(t & 3) * 8192];
    bf16x8 af[4], bfv[4];
#pragma unroll
    for (int i = 0; i < 4; ++i) {
      af[i] = *(const bf16x8*)&Sb[aoff + i * 512];
      bfv[i] = *(const bf16x8*)&Sb[boff + i * 512];
    }
#pragma unroll
    for (int i = 0; i < 4; ++i)
#pragma unroll
      for (int j = 0; j < 4; ++j)
        acc[i][j] = __builtin_amdgcn_mfma_f32_16x16x32_bf16(af[i], bfv[j], acc[i][j], 0, 0, 0);
    __builtin_amdgcn_sched_barrier(0);
    asm volatile("" ::: "memory");
    __builtin_amdgcn_s_barrier();  // all waves done reading buf[t&3]
    __builtin_amdgcn_sched_barrier(0);
    if (t + 4 < NT) {  // refill buf[t&3] with tile t+4
      u16* base = &S[(t & 3) * 8192 + wave * 512];
      const int kt = (t + 4) * 32;
      async_copy16(Ab + kt, base);
      async_copy16(Ab + K64 + kt, base + 2048);
      async_copy16(Bb + kt, base + 4096);
      async_copy16(Bb + K64 + kt, base + 6144);
    }
  }

  // C/D layout (verified m89/m91): col = lane&15, row = (lane>>4)*4 + reg
  float* Pf = SPLIT ? ((float*)Cout + (size_t)blockIdx.z * M * N) : (float*)Cout;
#pragma unroll
  for (int i = 0; i < 4; ++i) {
#pragma unroll
    for (int r = 0; r < 4; ++r) {
      const size_t grow = row0 + wm + i * 16 + quad * 4 + r;
      float bv = 0.f;
      if (BIAS && !SPLIT) bv = bias[grow];
      float rs = 1.f;
      if (SROW && !SPLIT) rs = scale[grow];
#pragma unroll
      for (int j = 0; j < 4; ++j) {
        const size_t gcol = col0 + wn + j * 16 + fr;
        float v = acc[i][j][r] + bv;
        if (SPLIT) {
          Pf[grow * N + gcol] = v;
        } else {
          if (SCOL) v *= scale[gcol];
          if (SROW) v *= rs;
          if (RELU) v = fmaxf(v, 0.f);
          if (OBF16)
            ((u16*)Cout)[grow * N + gcol] = f32_to_bf16(v);
          else
            ((float*)Cout)[grow * N + gcol] = v;
        }
      }
    }
  }
}

// Non-pipelined m97-structure GEMM — kept for the no-workspace fallback path.
template <bool RELU, bool BIAS, bool OBF16, bool SPLIT, bool SWIZ, bool SROW, bool SCOL>
__global__ __launch_bounds__(256) void gemm_bt(const u16* __restrict__ A,
                                               const u16* __restrict__ B,
                                               const float* __restrict__ bias,
                                               const float* __restrict__ scale,
                                               void* __restrict__ Cout,
                                               const int M, const int N, const int K,
                                               const int Kper) {
  __shared__ __attribute__((aligned(16))) u16 As[128 * 32];
  __shared__ __attribute__((aligned(16))) u16 Bs[128 * 32];
  const int tid = threadIdx.x;
  const int wave = tid >> 6;
  const int lane = tid & 63;

  int bx = blockIdx.x, by = blockIdx.y;
  if (SWIZ) {
    const int i2 = bx + gridDim.x * by;
    const int xcd = i2 & 7;
    const int slot = i2 >> 3;
    const int ypg = gridDim.y >> 3;
    by = xcd * ypg + (slot % ypg);
    bx = slot / ypg;
  }
  const size_t row0 = (size_t)by * 128;
  const size_t col0 = (size_t)bx * 128;
  const int kbeg = SPLIT ? blockIdx.z * Kper : 0;
  const int klen = SPLIT ? Kper : K;
  const int wm = (wave >> 1) << 6;
  const int wn = (wave & 1) << 6;

  f32x4 acc[4][4];
  const f32x4 zero = {0.f, 0.f, 0.f, 0.f};
#pragma unroll
  for (int i = 0; i < 4; ++i)
#pragma unroll
    for (int j = 0; j < 4; ++j) acc[i][j] = zero;

  const int e0 = wave * 512 + lane * 8;
  const int r0 = e0 >> 5;
  const int c0 = e0 & 31;
  const u16* Ab = A + row0 * K + (size_t)r0 * K + c0 + kbeg;
  const u16* Bb = B + col0 * K + (size_t)r0 * K + c0 + kbeg;
  u16* sA0 = &As[wave * 512];
  u16* sA1 = &As[2048 + wave * 512];
  u16* sB0 = &Bs[wave * 512];
  u16* sB1 = &Bs[2048 + wave * 512];
  const size_t K64 = (size_t)64 * K;

  const int fr = lane & 15;
  const int quad = lane >> 4;
  const int aoff = (wm + fr) * 32 + quad * 8;
  const int boff = (wn + fr) * 32 + quad * 8;

  for (int kt = 0; kt < klen; kt += 32) {
    async_copy16(Ab + kt, sA0);
    async_copy16(Ab + K64 + kt, sA1);
    async_copy16(Bb + kt, sB0);
    async_copy16(Bb + K64 + kt, sB1);
    __syncthreads();
    bf16x8 af[4], bfr[4];
#pragma unroll
    for (int i = 0; i < 4; ++i) {
      af[i] = *(const bf16x8*)&As[aoff + i * 512];
      bfr[i] = *(const bf16x8*)&Bs[boff + i * 512];
    }
#pragma unroll
    for (int i = 0; i < 4; ++i)
#pragma unroll
      for (int j = 0; j < 4; ++j)
        acc[i][j] = __builtin_amdgcn_mfma_f32_16x16x32_bf16(af[i], bfr[j], acc[i][j], 0, 0, 0);
    __syncthreads();
  }

  float* Pf = SPLIT ? ((float*)Cout + (size_t)blockIdx.z * M * N) : (float*)Cout;
#pragma unroll
  for (int i = 0; i < 4; ++i) {
#pragma unroll
    for (int r = 0; r < 4; ++r) {
      const size_t grow = row0 + wm + i * 16 + quad * 4 + r;
      float bv = 0.f;
      if (BIAS && !SPLIT) bv = bias[grow];
      float rs = 1.f;
      if (SROW && !SPLIT) rs = scale[grow];
#pragma unroll
      for (int j = 0; j < 4; ++j) {
        const size_t gcol = col0 + wn + j * 16 + fr;
        float v = acc[i][j][r] + bv;
        if (SPLIT) {
          Pf[grow * N + gcol] = v;
        } else {
          if (SCOL) v *= scale[gcol];
          if (SROW) v *= rs;
          if (RELU) v = fmaxf(v, 0.f);
          if (OBF16)
            ((u16*)Cout)[grow * N + gcol] = f32_to_bf16(v);
          else
            ((float*)Cout)[grow * N + gcol] = v;
        }
      }
    }
  }
}

// out = act( scale * (sum_s part[s] + bias) ), vectorized float4 per thread.
template <bool RELU, bool BIAS, bool OBF16, bool SROW, bool SCOL>
__global__ __launch_bounds__(256) void reduce_k(const float* __restrict__ part,
                                                const float* __restrict__ bias,
                                                const float* __restrict__ scale,
                                                void* __restrict__ out,
                                                const int M, const int N, const int ks) {
  const size_t MN4 = (size_t)M * N / 4;
  const size_t i4 = (size_t)blockIdx.x * 256 + threadIdx.x;
  if (i4 >= MN4) return;
  const float4* p4 = (const float4*)part;
  float4 s = p4[i4];
  for (int k = 1; k < ks; ++k) {
    float4 v = p4[(size_t)k * MN4 + i4];
    s.x += v.x; s.y += v.y; s.z += v.z; s.w += v.w;
  }
  const int row = (int)((i4 * 4) / N);
  if (BIAS) {
    const float b = bias[row];
    s.x += b; s.y += b; s.z += b; s.w += b;
  }
  if (SCOL) {
    const float4 sc = ((const float4*)scale)[i4 % (size_t)(N / 4)];
    s.x *= sc.x; s.y *= sc.y; s.z *= sc.z; s.w *= sc.w;
  }
  if (SROW) {
    const float r = scale[row];
    s.x *= r; s.y *= r; s.z *= r; s.w *= r;
  }
  if (RELU) {
    s.x = fmaxf(s.x, 0.f); s.y = fmaxf(s.y, 0.f);
    s.z = fmaxf(s.z, 0.f); s.w = fmaxf(s.w, 0.f);
  }
  if (OBF16) {
    ushort4 o;
    o.x = f32_to_bf16(s.x); o.y = f32_to_bf16(s.y);
    o.z = f32_to_bf16(s.z); o.w = f32_to_bf16(s.w);
    ((ushort4*)out)[i4] = o;
  } else {
    ((float4*)out)[i4] = s;
  }
}

extern "C" void kernel_launch(void* const* d_in, const int* in_sizes, int n_in,
                              void* d_out, int out_size, void* d_ws, size_t ws_size,
                              hipStream_t stream) {
  const float* point = (const float*)d_in[0];
  const float* edge  = (const float*)d_in[1];
  const float* W1    = (const float*)d_in[2];
  const float* b1    = (const float*)d_in[3];
  const float* W2    = (const float*)d_in[4];
  const float* b2    = (const float*)d_in[5];
  float* out = (float*)d_out;

  char* ws = (char*)d_ws;
  size_t off = 0;
  auto alloc = [&](size_t bytes) -> void* {
    void* p = ws + off;
    off += (bytes + 255) & ~(size_t)255;
    return p;
  };
  float* isq  = (float*)alloc((size_t)NN * 4);
  u16* Abf    = (u16*)alloc((size_t)NN * NN * 2);        // 128 MB (raw bf16 edge)
  // scratch (64 MB): pbf early; split-K partials reuse serially.
  char* scratch = (char*)alloc((size_t)64 * 1024 * 1024);
  u16* w1bf   = (u16*)alloc((size_t)HIDC * INC * 2);     // 1 MB
  u16* w2bf   = (u16*)alloc((size_t)OUTC * HIDC * 2);    // 0.5 MB
  u16* Ht     = (u16*)alloc((size_t)HIDC * NN * 2);      // 16 MB  (isq-scaled h1^T)
  u16* h2     = (u16*)alloc((size_t)NN * HIDC * 2);      // 16 MB  (relu(A_n h1))
  u16* O1t    = (u16*)alloc((size_t)OUTC * NN * 2);      // 4 MB   (isq-scaled o1^T)
  const bool have_ws = off <= ws_size;  // deterministic -> graph-safe

  u16* pbf = (u16*)scratch;             // 8 MB, dead after gemm1
  float* part = (float*)scratch;        // split-K partials

  // One pass over edge: rowsums (-> isq) + raw bf16 conversion.
  rowcvt_k<<<NN, 256, 0, stream>>>(edge, isq, Abf);
  f2bf_k<<<(NN * INC / 4) / 256, 256, 0, stream>>>(point, pbf, NN * INC / 4);
  f2bf_k<<<(HIDC * INC / 4) / 256, 256, 0, stream>>>(W1, w1bf, HIDC * INC / 4);
  f2bf_k<<<(OUTC * HIDC / 4) / 256, 256, 0, stream>>>(W2, w2bf, OUTC * HIDC / 4);

  if (have_ws) {
    // Ht[c][n] = isq[n]*(W1 @ point^T + b1): 64x8 = 512 blocks = 2/CU, NT=16
    gemm_pipe<false, true, true, false, false, false, true>
        <<<dim3(NN / 128, HIDC / 128), 256, 0, stream>>>(
        w1bf, pbf, b1, isq, Ht, HIDC, NN, INC, INC);

    // h2 = relu(isq[i]*(Abf @ Ht^T)): 8x64 = 512 blocks = 2/CU, NT=256,
    // swizzled (same-by blocks -> same XCD for A-panel L2 reuse).
    gemm_pipe<true, false, true, false, true, true, false>
        <<<dim3(HIDC / 128, NN / 128), 256, 0, stream>>>(
        Abf, Ht, nullptr, isq, h2, NN, HIDC, NN, NN);

    // O1t[c][n] = isq[n]*(W2 @ h2^T + b2): split-K 4 -> 64x2x4 = 512 blocks, NT=8
    gemm_pipe<false, false, false, true, false, false, false>
        <<<dim3(NN / 128, OUTC / 128, 4), 256, 0, stream>>>(
        w2bf, h2, nullptr, nullptr, part, OUTC, NN, HIDC, HIDC / 4);
    reduce_k<false, true, true, false, true><<<(OUTC * NN / 4) / 256, 256, 0, stream>>>(
        part, b2, isq, O1t, OUTC, NN, 4);

    // out = relu(isq[i]*(Abf @ O1t^T)): split-K 4 -> 2x64x4 = 512 blocks,
    // NT=64, swizzled. Partials 4 x 8 MB = 32 MB.
    gemm_pipe<false, false, false, true, true, false, false>
        <<<dim3(OUTC / 128, NN / 128, 4), 256, 0, stream>>>(
        Abf, O1t, nullptr, nullptr, part, NN, OUTC, NN, NN / 4);
    reduce_k<true, false, false, true, false><<<(NN * OUTC / 4) / 256, 256, 0, stream>>>(
        part, nullptr, isq, out, NN, OUTC, 4);
  } else {
    // fallback: non-split m97 path (no scratch partials beyond pbf)
    gemm_bt<false, true, true, false, false, false, true>
        <<<dim3(NN / 128, HIDC / 128), 256, 0, stream>>>(
        w1bf, pbf, b1, isq, Ht, HIDC, NN, INC, INC);
    gemm_bt<true, false, true, false, true, true, false>
        <<<dim3(HIDC / 128, NN / 128), 256, 0, stream>>>(
        Abf, Ht, nullptr, isq, h2, NN, HIDC, NN, NN);
    gemm_bt<false, true, true, false, false, false, true>
        <<<dim3(NN / 128, OUTC / 128), 256, 0, stream>>>(
        w2bf, h2, b2, isq, O1t, OUTC, NN, HIDC, HIDC);
    gemm_bt<true, false, false, false, true, true, false>
        <<<dim3(OUTC / 128, NN / 128), 256, 0, stream>>>(
        Abf, O1t, nullptr, isq, out, NN, OUTC, NN, NN);
  }
}

// Round 7
// 638.153 us; speedup vs baseline: 1.1620x; 1.0040x over previous
//
#include <hip/hip_runtime.h>
#include <cstdint>

#define NN 8192
#define INC 512
#define HIDC 1024
#define OUTC 256

typedef unsigned short u16;
typedef __attribute__((ext_vector_type(8))) __bf16 bf16x8;
typedef __attribute__((ext_vector_type(4))) float f32x4;

__device__ __forceinline__ u16 f32_to_bf16(float f) {
  union { float f; unsigned u; } c; c.f = f;
  unsigned u = c.u;
  u += 0x7fffu + ((u >> 16) & 1u);   // round-to-nearest-even
  return (u16)(u >> 16);
}

// async global->LDS, 16B/lane. LDS dest is wave-uniform base + lane*16.
__device__ __forceinline__ void async_copy16(const void* g, void* l) {
  typedef __attribute__((address_space(1))) const char gch;
  typedef __attribute__((address_space(3))) char lch;
  __builtin_amdgcn_global_load_lds((gch*)(uint64_t)(uintptr_t)g,
                                   (lch*)(uint32_t)(uintptr_t)l, 16, 0, 0);
}

// Fused: deg[i] = sum_j edge[i][j]; isq[i] = deg>0 ? 1/sqrt(deg) : 0;
// Abf[i][j] = bf16(edge[i][j])  (RAW, unnormalized — D^-1/2 scales are folded
// into the GEMM epilogues; valid since relu(s*x) = s*relu(x) for s >= 0).
__global__ __launch_bounds__(256) void rowcvt_k(const float* __restrict__ edge,
                                                float* __restrict__ isq,
                                                u16* __restrict__ Abf) {
  __shared__ float red[4];
  const int row = blockIdx.x;
  const float4* e4 = (const float4*)(edge + (size_t)row * NN);
  ushort4* o4 = (ushort4*)(Abf + (size_t)row * NN);
  float s = 0.f;
#pragma unroll
  for (int it = 0; it < NN / 4 / 256; ++it) {
    float4 v = e4[it * 256 + threadIdx.x];
    s += (v.x + v.y) + (v.z + v.w);
    ushort4 o;
    o.x = f32_to_bf16(v.x);
    o.y = f32_to_bf16(v.y);
    o.z = f32_to_bf16(v.z);
    o.w = f32_to_bf16(v.w);
    o4[it * 256 + threadIdx.x] = o;
  }
  for (int off = 32; off > 0; off >>= 1) s += __shfl_down(s, off, 64);
  if ((threadIdx.x & 63) == 0) red[threadIdx.x >> 6] = s;
  __syncthreads();
  if (threadIdx.x == 0) {
    float t = (red[0] + red[1]) + (red[2] + red[3]);
    isq[row] = (t > 0.f) ? (1.0f / sqrtf(t)) : 0.f;
  }
}

__global__ __launch_bounds__(256) void f2bf_k(const float* __restrict__ in,
                                              u16* __restrict__ out, int n4) {
  int i = blockIdx.x * 256 + threadIdx.x;
  if (i >= n4) return;
  float4 v = ((const float4*)in)[i];
  ushort4 o;
  o.x = f32_to_bf16(v.x);
  o.y = f32_to_bf16(v.y);
  o.z = f32_to_bf16(v.z);
  o.w = f32_to_bf16(v.w);
  ((ushort4*)out)[i] = o;
}

// ---------------------------------------------------------------------------
// Pipelined GEMM, 128x128 tile, 2 blocks/CU, SWIZZLED LDS:
// C[M,N] = act(scale*(A[M,K] @ B[N,K]^T + bias)); A,B bf16 row-major.
// 4 waves (64x64 quadrant each, 4x4 16x16x32 MFMA), depth-4 LDS pipeline
// (4 x 16 KB = 64 KB), counted vmcnt(12), raw s_barrier.
//
// LDS swizzle (R4 counters: 16.78M bank-conflict cycles = +4 cy on every
// ds_read_b128; fragment reads put each 32-lane phase on only 4 of 8
// 16B-granule groups -> half the banks idle). Fix per rule 21: LDS dest
// stays linear (global_load_lds requirement); each lane PRE-SWIZZLES its
// global source chunk, and reads XOR the slot index:
//   physical slot s = logical slot ^ ((row>>1)&3)   (4 x 16B slots / row)
// Staging lane l: logical chunk = (l&3) ^ ((l>>3)&3) of its row (row =
// w*16 + (l>>2), so (row>>1)&3 = (l>>3)&3). Same 64B segment per 4-lane
// group -> global coalescing preserved. Read: slot = quad ^ ((fr>>1)&3)
// (invariant under +16i rows / wm since those add multiples of 8 to row>>1).
// Pure address permutation -> absmax must be unchanged.
// ---------------------------------------------------------------------------
template <bool RELU, bool BIAS, bool OBF16, bool SPLIT, bool SWIZ, bool SROW, bool SCOL>
__global__ __launch_bounds__(256, 2) void gemm_pipe(const u16* __restrict__ A,
                                                    const u16* __restrict__ B,
                                                    const float* __restrict__ bias,
                                                    const float* __restrict__ scale,
                                                    void* __restrict__ Cout,
                                                    const int M, const int N,
                                                    const int K, const int Kper) {
  // buffer p: A tile 128x32 at [p*8192, +4096), B tile 128x32 at +4096.
  __shared__ __attribute__((aligned(16))) u16 S[4 * 8192];
  const int tid = threadIdx.x;
  const int wave = tid >> 6;
  const int lane = tid & 63;

  int bx = blockIdx.x, by = blockIdx.y;
  if (SWIZ) {  // gridDim.y % 8 == 0; same-y blocks share one XCD's L2
    const int i2 = bx + gridDim.x * by;
    const int xcd = i2 & 7;
    const int slot = i2 >> 3;
    const int ypg = gridDim.y >> 3;
    by = xcd * ypg + (slot % ypg);
    bx = slot / ypg;
  }
  const size_t row0 = (size_t)by * 128;
  const size_t col0 = (size_t)bx * 128;
  const int kbeg = SPLIT ? blockIdx.z * Kper : 0;
  const int klen = SPLIT ? Kper : K;
  const int NT = klen / 32;
  const int wm = (wave >> 1) << 6;  // wave quadrant: 64x64
  const int wn = (wave & 1) << 6;

  f32x4 acc[4][4];
  const f32x4 zero = {0.f, 0.f, 0.f, 0.f};
#pragma unroll
  for (int i = 0; i < 4; ++i)
#pragma unroll
    for (int j = 0; j < 4; ++j) acc[i][j] = zero;

  // staging map: lane l covers tile row w*16 + (l>>2); its LDS slot is l&3,
  // holding logical (global) chunk (l&3) ^ ((l>>3)&3)  [slot swizzle].
  const int r0 = wave * 16 + (lane >> 2);
  const int c0 = ((lane & 3) ^ ((lane >> 3) & 3)) * 8;  // element col in tile
  const u16* Ab = A + (row0 + r0) * K + c0 + kbeg;
  const u16* Bb = B + (col0 + r0) * K + c0 + kbeg;
  const size_t K64 = (size_t)64 * K;

  // prologue: stage tiles 0..3 into buffers 0..3 (4 loads/wave each)
#pragma unroll
  for (int p = 0; p < 4; ++p) {
    if (p < NT) {
      u16* base = &S[p * 8192 + wave * 512];
      const int kt = p * 32;
      async_copy16(Ab + kt, base);
      async_copy16(Ab + K64 + kt, base + 2048);
      async_copy16(Bb + kt, base + 4096);
      async_copy16(Bb + K64 + kt, base + 6144);
    }
  }

  const int fr = lane & 15;
  const int quad = lane >> 4;
  const int sl = (quad ^ ((fr >> 1) & 3)) * 8;  // swizzled 16B slot
  const int aoff = (wm + fr) * 32 + sl;
  const int boff = 4096 + (wn + fr) * 32 + sl;

  for (int t = 0; t < NT; ++t) {
    // 3 newer tiles (12 loads) may stay in flight; tile t must be done.
    asm volatile("s_waitcnt vmcnt(12)" ::: "memory");
    __builtin_amdgcn_sched_barrier(0);
    __builtin_amdgcn_s_barrier();  // now ALL waves' tile-t loads are in LDS
    asm volatile("" ::: "memory");
    const u16* Sb = &S[(t & 3) * 8192];
    bf16x8 af[4], bfv[4];
#pragma unroll
    for (int i = 0; i < 4; ++i) {
      af[i] = *(const bf16x8*)&Sb[aoff + i * 512];
      bfv[i] = *(const bf16x8*)&Sb[boff + i * 512];
    }
#pragma unroll
    for (int i = 0; i < 4; ++i)
#pragma unroll
      for (int j = 0; j < 4; ++j)
        acc[i][j] = __builtin_amdgcn_mfma_f32_16x16x32_bf16(af[i], bfv[j], acc[i][j], 0, 0, 0);
    __builtin_amdgcn_sched_barrier(0);
    asm volatile("" ::: "memory");
    __builtin_amdgcn_s_barrier();  // all waves done reading buf[t&3]
    __builtin_amdgcn_sched_barrier(0);
    if (t + 4 < NT) {  // refill buf[t&3] with tile t+4
      u16* base = &S[(t & 3) * 8192 + wave * 512];
      const int kt = (t + 4) * 32;
      async_copy16(Ab + kt, base);
      async_copy16(Ab + K64 + kt, base + 2048);
      async_copy16(Bb + kt, base + 4096);
      async_copy16(Bb + K64 + kt, base + 6144);
    }
  }

  // C/D layout (verified m89/m91): col = lane&15, row = (lane>>4)*4 + reg
  float* Pf = SPLIT ? ((float*)Cout + (size_t)blockIdx.z * M * N) : (float*)Cout;
#pragma unroll
  for (int i = 0; i < 4; ++i) {
#pragma unroll
    for (int r = 0; r < 4; ++r) {
      const size_t grow = row0 + wm + i * 16 + quad * 4 + r;
      float bv = 0.f;
      if (BIAS && !SPLIT) bv = bias[grow];
      float rs = 1.f;
      if (SROW && !SPLIT) rs = scale[grow];
#pragma unroll
      for (int j = 0; j < 4; ++j) {
        const size_t gcol = col0 + wn + j * 16 + fr;
        float v = acc[i][j][r] + bv;
        if (SPLIT) {
          Pf[grow * N + gcol] = v;
        } else {
          if (SCOL) v *= scale[gcol];
          if (SROW) v *= rs;
          if (RELU) v = fmaxf(v, 0.f);
          if (OBF16)
            ((u16*)Cout)[grow * N + gcol] = f32_to_bf16(v);
          else
            ((float*)Cout)[grow * N + gcol] = v;
        }
      }
    }
  }
}

// Non-pipelined m97-structure GEMM — kept for the no-workspace fallback path.
// (Also carries the slot swizzle; same staging/read geometry.)
template <bool RELU, bool BIAS, bool OBF16, bool SPLIT, bool SWIZ, bool SROW, bool SCOL>
__global__ __launch_bounds__(256) void gemm_bt(const u16* __restrict__ A,
                                               const u16* __restrict__ B,
                                               const float* __restrict__ bias,
                                               const float* __restrict__ scale,
                                               void* __restrict__ Cout,
                                               const int M, const int N, const int K,
                                               const int Kper) {
  __shared__ __attribute__((aligned(16))) u16 As[128 * 32];
  __shared__ __attribute__((aligned(16))) u16 Bs[128 * 32];
  const int tid = threadIdx.x;
  const int wave = tid >> 6;
  const int lane = tid & 63;

  int bx = blockIdx.x, by = blockIdx.y;
  if (SWIZ) {
    const int i2 = bx + gridDim.x * by;
    const int xcd = i2 & 7;
    const int slot = i2 >> 3;
    const int ypg = gridDim.y >> 3;
    by = xcd * ypg + (slot % ypg);
    bx = slot / ypg;
  }
  const size_t row0 = (size_t)by * 128;
  const size_t col0 = (size_t)bx * 128;
  const int kbeg = SPLIT ? blockIdx.z * Kper : 0;
  const int klen = SPLIT ? Kper : K;
  const int wm = (wave >> 1) << 6;
  const int wn = (wave & 1) << 6;

  f32x4 acc[4][4];
  const f32x4 zero = {0.f, 0.f, 0.f, 0.f};
#pragma unroll
  for (int i = 0; i < 4; ++i)
#pragma unroll
    for (int j = 0; j < 4; ++j) acc[i][j] = zero;

  const int r0 = wave * 16 + (lane >> 2);
  const int c0 = ((lane & 3) ^ ((lane >> 3) & 3)) * 8;
  const u16* Ab = A + (row0 + r0) * K + c0 + kbeg;
  const u16* Bb = B + (col0 + r0) * K + c0 + kbeg;
  u16* sA0 = &As[wave * 512];
  u16* sA1 = &As[2048 + wave * 512];
  u16* sB0 = &Bs[wave * 512];
  u16* sB1 = &Bs[2048 + wave * 512];
  const size_t K64 = (size_t)64 * K;

  const int fr = lane & 15;
  const int quad = lane >> 4;
  const int sl = (quad ^ ((fr >> 1) & 3)) * 8;
  const int aoff = (wm + fr) * 32 + sl;
  const int boff = (wn + fr) * 32 + sl;

  for (int kt = 0; kt < klen; kt += 32) {
    async_copy16(Ab + kt, sA0);
    async_copy16(Ab + K64 + kt, sA1);
    async_copy16(Bb + kt, sB0);
    async_copy16(Bb + K64 + kt, sB1);
    __syncthreads();
    bf16x8 af[4], bfr[4];
#pragma unroll
    for (int i = 0; i < 4; ++i) {
      af[i] = *(const bf16x8*)&As[aoff + i * 512];
      bfr[i] = *(const bf16x8*)&Bs[boff + i * 512];
    }
#pragma unroll
    for (int i = 0; i < 4; ++i)
#pragma unroll
      for (int j = 0; j < 4; ++j)
        acc[i][j] = __builtin_amdgcn_mfma_f32_16x16x32_bf16(af[i], bfr[j], acc[i][j], 0, 0, 0);
    __syncthreads();
  }

  float* Pf = SPLIT ? ((float*)Cout + (size_t)blockIdx.z * M * N) : (float*)Cout;
#pragma unroll
  for (int i = 0; i < 4; ++i) {
#pragma unroll
    for (int r = 0; r < 4; ++r) {
      const size_t grow = row0 + wm + i * 16 + quad * 4 + r;
      float bv = 0.f;
      if (BIAS && !SPLIT) bv = bias[grow];
      float rs = 1.f;
      if (SROW && !SPLIT) rs = scale[grow];
#pragma unroll
      for (int j = 0; j < 4; ++j) {
        const size_t gcol = col0 + wn + j * 16 + fr;
        float v = acc[i][j][r] + bv;
        if (SPLIT) {
          Pf[grow * N + gcol] = v;
        } else {
          if (SCOL) v *= scale[gcol];
          if (SROW) v *= rs;
          if (RELU) v = fmaxf(v, 0.f);
          if (OBF16)
            ((u16*)Cout)[grow * N + gcol] = f32_to_bf16(v);
          else
            ((float*)Cout)[grow * N + gcol] = v;
        }
      }
    }
  }
}

// out = act( scale * (sum_s part[s] + bias) ), vectorized float4 per thread.
template <bool RELU, bool BIAS, bool OBF16, bool SROW, bool SCOL>
__global__ __launch_bounds__(256) void reduce_k(const float* __restrict__ part,
                                                const float* __restrict__ bias,
                                                const float* __restrict__ scale,
                                                void* __restrict__ out,
                                                const int M, const int N, const int ks) {
  const size_t MN4 = (size_t)M * N / 4;
  const size_t i4 = (size_t)blockIdx.x * 256 + threadIdx.x;
  if (i4 >= MN4) return;
  const float4* p4 = (const float4*)part;
  float4 s = p4[i4];
  for (int k = 1; k < ks; ++k) {
    float4 v = p4[(size_t)k * MN4 + i4];
    s.x += v.x; s.y += v.y; s.z += v.z; s.w += v.w;
  }
  const int row = (int)((i4 * 4) / N);
  if (BIAS) {
    const float b = bias[row];
    s.x += b; s.y += b; s.z += b; s.w += b;
  }
  if (SCOL) {
    const float4 sc = ((const float4*)scale)[i4 % (size_t)(N / 4)];
    s.x *= sc.x; s.y *= sc.y; s.z *= sc.z; s.w *= sc.w;
  }
  if (SROW) {
    const float r = scale[row];
    s.x *= r; s.y *= r; s.z *= r; s.w *= r;
  }
  if (RELU) {
    s.x = fmaxf(s.x, 0.f); s.y = fmaxf(s.y, 0.f);
    s.z = fmaxf(s.z, 0.f); s.w = fmaxf(s.w, 0.f);
  }
  if (OBF16) {
    ushort4 o;
    o.x = f32_to_bf16(s.x); o.y = f32_to_bf16(s.y);
    o.z = f32_to_bf16(s.z); o.w = f32_to_bf16(s.w);
    ((ushort4*)out)[i4] = o;
  } else {
    ((float4*)out)[i4] = s;
  }
}

extern "C" void kernel_launch(void* const* d_in, const int* in_sizes, int n_in,
                              void* d_out, int out_size, void* d_ws, size_t ws_size,
                              hipStream_t stream) {
  const float* point = (const float*)d_in[0];
  const float* edge  = (const float*)d_in[1];
  const float* W1    = (const float*)d_in[2];
  const float* b1    = (const float*)d_in[3];
  const float* W2    = (const float*)d_in[4];
  const float* b2    = (const float*)d_in[5];
  float* out = (float*)d_out;

  char* ws = (char*)d_ws;
  size_t off = 0;
  auto alloc = [&](size_t bytes) -> void* {
    void* p = ws + off;
    off += (bytes + 255) & ~(size_t)255;
    return p;
  };
  float* isq  = (float*)alloc((size_t)NN * 4);
  u16* Abf    = (u16*)alloc((size_t)NN * NN * 2);        // 128 MB (raw bf16 edge)
  // scratch (64 MB): pbf early; split-K partials reuse serially.
  char* scratch = (char*)alloc((size_t)64 * 1024 * 1024);
  u16* w1bf   = (u16*)alloc((size_t)HIDC * INC * 2);     // 1 MB
  u16* w2bf   = (u16*)alloc((size_t)OUTC * HIDC * 2);    // 0.5 MB
  u16* Ht     = (u16*)alloc((size_t)HIDC * NN * 2);      // 16 MB  (isq-scaled h1^T)
  u16* h2     = (u16*)alloc((size_t)NN * HIDC * 2);      // 16 MB  (relu(A_n h1))
  u16* O1t    = (u16*)alloc((size_t)OUTC * NN * 2);      // 4 MB   (isq-scaled o1^T)
  const bool have_ws = off <= ws_size;  // deterministic -> graph-safe

  u16* pbf = (u16*)scratch;             // 8 MB, dead after gemm1
  float* part = (float*)scratch;        // split-K partials

  // One pass over edge: rowsums (-> isq) + raw bf16 conversion.
  rowcvt_k<<<NN, 256, 0, stream>>>(edge, isq, Abf);
  f2bf_k<<<(NN * INC / 4) / 256, 256, 0, stream>>>(point, pbf, NN * INC / 4);
  f2bf_k<<<(HIDC * INC / 4) / 256, 256, 0, stream>>>(W1, w1bf, HIDC * INC / 4);
  f2bf_k<<<(OUTC * HIDC / 4) / 256, 256, 0, stream>>>(W2, w2bf, OUTC * HIDC / 4);

  if (have_ws) {
    // Ht[c][n] = isq[n]*(W1 @ point^T + b1): 64x8 = 512 blocks = 2/CU, NT=16
    gemm_pipe<false, true, true, false, false, false, true>
        <<<dim3(NN / 128, HIDC / 128), 256, 0, stream>>>(
        w1bf, pbf, b1, isq, Ht, HIDC, NN, INC, INC);

    // h2 = relu(isq[i]*(Abf @ Ht^T)): 8x64 = 512 blocks = 2/CU, NT=256,
    // swizzled (same-by blocks -> same XCD for A-panel L2 reuse).
    gemm_pipe<true, false, true, false, true, true, false>
        <<<dim3(HIDC / 128, NN / 128), 256, 0, stream>>>(
        Abf, Ht, nullptr, isq, h2, NN, HIDC, NN, NN);

    // O1t[c][n] = isq[n]*(W2 @ h2^T + b2): split-K 4 -> 64x2x4 = 512 blocks, NT=8
    gemm_pipe<false, false, false, true, false, false, false>
        <<<dim3(NN / 128, OUTC / 128, 4), 256, 0, stream>>>(
        w2bf, h2, nullptr, nullptr, part, OUTC, NN, HIDC, HIDC / 4);
    reduce_k<false, true, true, false, true><<<(OUTC * NN / 4) / 256, 256, 0, stream>>>(
        part, b2, isq, O1t, OUTC, NN, 4);

    // out = relu(isq[i]*(Abf @ O1t^T)): split-K 4 -> 2x64x4 = 512 blocks,
    // NT=64, swizzled. Partials 4 x 8 MB = 32 MB.
    gemm_pipe<false, false, false, true, true, false, false>
        <<<dim3(OUTC / 128, NN / 128, 4), 256, 0, stream>>>(
        Abf, O1t, nullptr, nullptr, part, NN, OUTC, NN, NN / 4);
    reduce_k<true, false, false, true, false><<<(NN * OUTC / 4) / 256, 256, 0, stream>>>(
        part, nullptr, isq, out, NN, OUTC, 4);
  } else {
    // fallback: non-split m97 path (no scratch partials beyond pbf)
    gemm_bt<false, true, true, false, false, false, true>
        <<<dim3(NN / 128, HIDC / 128), 256, 0, stream>>>(
        w1bf, pbf, b1, isq, Ht, HIDC, NN, INC, INC);
    gemm_bt<true, false, true, false, true, true, false>
        <<<dim3(HIDC / 128, NN / 128), 256, 0, stream>>>(
        Abf, Ht, nullptr, isq, h2, NN, HIDC, NN, NN);
    gemm_bt<false, true, true, false, false, false, true>
        <<<dim3(NN / 128, OUTC / 128), 256, 0, stream>>>(
        w2bf, h2, b2, isq, O1t, OUTC, NN, HIDC, HIDC);
    gemm_bt<true, false, false, false, true, true, false>
        <<<dim3(OUTC / 128, NN / 128), 256, 0, stream>>>(
        Abf, O1t, nullptr, isq, out, NN, OUTC, NN, NN);
  }
}